// Round 1
// baseline (1420.588 us; speedup 1.0000x reference)
//
#include <hip/hip_runtime.h>
#include <cmath>
#include <complex>
#include <cstdio>
#include <algorithm>

#define E_EDGES 32768
#define NNODES  2048

// ============================ host-side CG tables ============================
namespace cgt {

static double fct(int n){
  static const double f[13] = {1.,1.,2.,6.,24.,120.,720.,5040.,40320.,362880.,
                               3628800.,39916800.,479001600.};
  return f[n];
}

static double cg(int j1,int m1,int j2,int m2,int j3,int m3){
  if (m1+m2 != m3) return 0.0;
  double pre = std::sqrt((2*j3+1)*fct(j1+j2-j3)*fct(j1-j2+j3)*fct(-j1+j2+j3)/fct(j1+j2+j3+1));
  pre *= std::sqrt(fct(j3+m3)*fct(j3-m3)*fct(j1-m1)*fct(j1+m1)*fct(j2-m2)*fct(j2+m2));
  int kmin = 0;
  if (j2-j3-m1 > kmin) kmin = j2-j3-m1;
  if (j1-j3+m2 > kmin) kmin = j1-j3+m2;
  int kmax = j1+j2-j3;
  if (j1-m1 < kmax) kmax = j1-m1;
  if (j2+m2 < kmax) kmax = j2+m2;
  double s = 0.0;
  for (int k=kmin;k<=kmax;k++){
    double d = fct(k)*fct(j1+j2-j3-k)*fct(j1-m1-k)*fct(j2+m2-k)*fct(j3-j2+m1+k)*fct(j3-j1-m2+k);
    s += ((k&1)? -1.0:1.0)/d;
  }
  return pre*s;
}

typedef std::complex<double> cd;

static void umat(int l, cd U[7][7]){
  for (int a=0;a<7;a++) for (int b=0;b<7;b++) U[a][b]=cd(0,0);
  U[l][l] = cd(1,0);
  double s2 = 1.0/std::sqrt(2.0);
  for (int m=1;m<=l;m++){
    double sg = (m&1)? -1.0 : 1.0;
    U[l+m][l-m] = cd(s2,0);
    U[l+m][l+m] = cd(sg*s2,0);
    U[l-m][l-m] = cd(0, s2);
    U[l-m][l+m] = cd(0, -sg*s2);
  }
}

struct Tables {
  float val[4096];
  int   ijk[4096];
  int   pmeta[40*4];   // per path: tpOff, entStart, entCount, kdim
  int   l3base[4];
  int   l3np[4];
  int   npaths;
  int   nent;
  int   tptot;
};

static bool realCoupling(int l1,int l2,int l3, double T[7][7][7]){
  cd U1[7][7],U2[7][7],U3[7][7];
  umat(l1,U1); umat(l2,U2); umat(l3,U3);
  int n1=2*l1+1, n2=2*l2+1, n3=2*l3+1;
  double Cg[7][7][7];
  for (int m=0;m<n1;m++) for(int n=0;n<n2;n++) for(int k=0;k<n3;k++)
    Cg[m][n][k] = cg(l1,m-l1,l2,n-l2,l3,k-l3);
  double Tr[7][7][7], Ti[7][7][7];
  double nr=0, ni=0;
  for (int a=0;a<n1;a++) for(int b=0;b<n2;b++) for(int c=0;c<n3;c++){
    cd s(0,0);
    for (int m=0;m<n1;m++){
      if (U1[a][m]==cd(0,0)) continue;
      for (int n=0;n<n2;n++){
        if (U2[b][n]==cd(0,0)) continue;
        for (int k=0;k<n3;k++){
          double cgv = Cg[m][n][k];
          if (cgv==0.0) continue;
          s += U1[a][m]*U2[b][n]*std::conj(U3[c][k])*cgv;
        }
      }
    }
    Tr[a][b][c]=s.real(); Ti[a][b][c]=s.imag();
    nr += s.real()*s.real(); ni += s.imag()*s.imag();
  }
  bool useR = (nr >= ni);
  double nn = std::sqrt(useR? nr : ni);
  if (nn < 1e-8) return false;
  for (int a=0;a<n1;a++)for(int b=0;b<n2;b++)for(int c=0;c<n3;c++)
    T[a][b][c] = (useR? Tr[a][b][c] : Ti[a][b][c])/nn;
  return true;
}

static void build(Tables& tb){
  int tpoff = 0, ep = 0, pg = 0;
  for (int l3=0;l3<=3;l3++){
    tb.l3base[l3] = tpoff;
    int np = 0;
    int kd = 2*l3+1;
    double scale = std::sqrt((double)(2*l3+1));
    for (int l1=0;l1<=3;l1++) for (int l2=0;l2<=3;l2++){
      int lo = (l1>l2)? l1-l2 : l2-l1;
      int hi = std::min(l1+l2,3);
      if (l3 < lo || l3 > hi) continue;
      double T[7][7][7];
      if (!realCoupling(l1,l2,l3,T)) continue;
      tb.pmeta[pg*4+0] = tpoff;
      tb.pmeta[pg*4+1] = ep;
      int cnt = 0;
      int s1 = l1*l1, s2 = l2*l2;   // SL slice starts: 0,1,4,9
      for (int a=0;a<2*l1+1;a++)for(int b=0;b<2*l2+1;b++)for(int c=0;c<kd;c++){
        double v = T[a][b][c]*scale;
        if (std::fabs(v) > 1e-7){
          tb.val[ep] = (float)v;
          tb.ijk[ep] = (s1+a) | ((s2+b)<<8) | (c<<16);
          ep++; cnt++;
        }
      }
      tb.pmeta[pg*4+2] = cnt;
      tb.pmeta[pg*4+3] = kd;
      tpoff += 16*kd;
      pg++; np++;
    }
    tb.l3np[l3] = np;
  }
  tb.npaths = pg; tb.nent = ep; tb.tptot = tpoff;
}

} // namespace cgt

// ============================ device kernels ============================

enum GFlags { F_NONE=0, F_SILU=1, F_ENV=2, F_RESID=4 };

// Generic tiled GEMM: C[M,N] = post( A[M,K] @ W[K,N] / sqrt(K) )
// A is split-source: cols [0,K1) from A1 (stride K1), cols [K1,K) from A2 (stride K-K1).
template<int FLAGS>
__global__ __launch_bounds__(256) void gemm_k(
    const float* __restrict__ A1, const float* __restrict__ A2,
    int K1, int K, const float* __restrict__ W, int N,
    float* Cout,
    const float* __restrict__ env, const float* __restrict__ alphap,
    const float* Xres)
{
  __shared__ float As[16][68];
  __shared__ float Ws[16][68];
  const int tid = threadIdx.x;
  const int bm = blockIdx.x * 64;
  const int bn = blockIdx.y * 64;
  const int tx = tid & 15, ty = tid >> 4;
  const int K2 = K - K1;
  float acc[4][4] = {};
  for (int k0 = 0; k0 < K; k0 += 16) {
#pragma unroll
    for (int i = 0; i < 4; i++) {
      int idx = tid + i*256;
      int m = idx >> 4, kk = idx & 15;
      int k = k0 + kk;
      float v = 0.f;
      if (k < K) {
        int row = bm + m;
        v = (k < K1) ? A1[(size_t)row*K1 + k] : A2[(size_t)row*K2 + (k-K1)];
      }
      As[kk][m] = v;
    }
#pragma unroll
    for (int i = 0; i < 4; i++) {
      int idx = tid + i*256;
      int n = idx & 63, kk = idx >> 6;
      int k = k0 + kk, col = bn + n;
      Ws[kk][n] = (k < K && col < N) ? W[(size_t)k*N + col] : 0.f;
    }
    __syncthreads();
#pragma unroll
    for (int kk = 0; kk < 16; kk++) {
      float a[4], b[4];
#pragma unroll
      for (int i=0;i<4;i++) a[i] = As[kk][ty*4+i];
#pragma unroll
      for (int j=0;j<4;j++) b[j] = Ws[kk][tx*4+j];
#pragma unroll
      for (int i=0;i<4;i++)
#pragma unroll
        for (int j=0;j<4;j++)
          acc[i][j] += a[i]*b[j];
    }
    __syncthreads();
  }
  const float rscale = 1.f/sqrtf((float)K);
  float a2 = 0.f, inv1a2 = 1.f;
  if (FLAGS & F_RESID) { float al = alphap[0]; a2 = al*al; inv1a2 = 1.f/(1.f+a2); }
#pragma unroll
  for (int i=0;i<4;i++) {
    int row = bm + ty*4 + i;
    float ev = (FLAGS & F_ENV) ? env[row] : 1.f;
#pragma unroll
    for (int j=0;j<4;j++) {
      int col = bn + tx*4 + j;
      if (col >= N) continue;
      float v = acc[i][j]*rscale;
      if (FLAGS & F_SILU) v = v/(1.f+__expf(-v));
      if (FLAGS & F_ENV)  v *= ev;
      if (FLAGS & F_RESID) v = (Xres[(size_t)row*N+col] + a2*v)*inv1a2;
      Cout[(size_t)row*N+col] = v;
    }
  }
}

// dense to 16 outputs, K=256 fixed, scale 1/16, no activation
__global__ __launch_bounds__(256) void dense16_k(const float* __restrict__ A,
    const float* __restrict__ W, float* __restrict__ C)
{
  __shared__ float As[16*256];
  const int r0 = blockIdx.x << 4;
  const int tid = threadIdx.x;
  for (int i = tid; i < 16*256; i += 256)
    As[i] = A[((size_t)r0<<8) + i];
  __syncthreads();
  const int r = tid >> 4, n = tid & 15;
  float acc = 0.f;
#pragma unroll 8
  for (int k = 0; k < 256; k++)
    acc += As[(r<<8)+k] * W[(k<<4)+n];
  C[((size_t)(r0+r)<<4)+n] = acc * 0.0625f;
}

__global__ void edge_init_k(const float* __restrict__ vectors, const int* __restrict__ senders,
    const int* __restrict__ receivers, const int* __restrict__ species,
    const float* __restrict__ emb, float* __restrict__ envb, float* __restrict__ Yb,
    float* __restrict__ x72)
{
  const int e = blockIdx.x*256 + threadIdx.x;
  float vx = vectors[e*3+0], vy = vectors[e*3+1], vz = vectors[e*3+2];
  float d = sqrtf(vx*vx+vy*vy+vz*vz);
  float dd = (d==0.f) ? 1.f : d;
  float invd = 1.f/dd;
  float x = vx*invd, y = vy*invd, z = vz*invd;
  float d2=d*d, d3=d2*d, d6=d3*d3, d7=d6*d, d8=d7*d;
  float envv = (d<1.f) ? (1.f - 28.f*d6 + 48.f*d7 - 21.f*d8) : 0.f;
  envb[e] = envv;
  float mask = (d==0.f)?0.f:1.f;
  const float SQ2 = 1.41421356237309515f;
  const float PIf = 3.14159265358979323846f;
  float* xr = x72 + (size_t)e*72;
#pragma unroll
  for (int n=1;n<=8;n++)
    xr[n-1] = SQ2 * sinf((float)n*PIf*dd)*invd*envv*mask;
  int sp_s = species[senders[e]], sp_r = species[receivers[e]];
  const float* es_ = emb + (size_t)sp_s*32;
  const float* er_ = emb + (size_t)sp_r*32;
#pragma unroll 8
  for (int k=0;k<32;k++){ xr[8+k] = es_[k]*mask; xr[40+k] = er_[k]*mask; }
  // real spherical harmonics up to l=3
  float x2=x*x, y2=y*y, z2=z*z;
  const float s3=1.7320508075688772f, s15=3.872983346207417f, s5=2.23606797749979f;
  const float s358=2.0916500663351889f, s105=10.246950765959598f;
  const float s218=1.6201851746019651f, s7=2.6457513110645907f;
  float* Yr = Yb + ((size_t)e<<4);
  Yr[0]=1.f;           Yr[1]=s3*y;          Yr[2]=s3*z;           Yr[3]=s3*x;
  Yr[4]=s15*x*y;       Yr[5]=s15*y*z;       Yr[6]=0.5f*s5*(3.f*z2-1.f);
  Yr[7]=s15*x*z;       Yr[8]=0.5f*s15*(x2-y2);
  Yr[9]=s358*y*(3.f*x2-y2);  Yr[10]=s105*x*y*z;  Yr[11]=s218*y*(5.f*z2-1.f);
  Yr[12]=0.5f*s7*(5.f*z2-3.f)*z;  Yr[13]=s218*x*(5.f*z2-1.f);
  Yr[14]=0.5f*s105*(x2-y2)*z;     Yr[15]=s358*x*(x2-y2);
}

// V[e,m,k] = w0[e,m]*Y[e,k]
__global__ void vinit_k(const float* __restrict__ w0, const float* __restrict__ Y,
                        float* __restrict__ V)
{
  const int gid = blockIdx.x*256 + threadIdx.x;
  const int e = gid >> 8, idx = gid & 255;
  V[gid] = w0[(e<<4)+(idx>>4)] * Y[(e<<4)+(idx&15)];
}

// node[senders[e], m, k] += w[e,m]*Y[e,k]
__global__ void scatter_k(const float* __restrict__ w, const float* __restrict__ Y,
                          const int* __restrict__ senders, float* node)
{
  const int gid = blockIdx.x*256 + threadIdx.x;
  const int e = gid >> 8, idx = gid & 255;
  float v = w[(e<<4) + (idx>>4)] * Y[(e<<4) + (idx&15)];
  atomicAdd(&node[((size_t)senders[e]<<8) + idx], v);
}

// layer-1 TP: full tensor product into LDS, then dense_axis -> Vn, plus tp0 out.
__global__ __launch_bounds__(256) void tp1_k(
    const float* __restrict__ node, const float* V,
    const int* __restrict__ senders, const float* __restrict__ varepsp,
    const int* __restrict__ pmeta, const int* __restrict__ entIJK,
    const float* __restrict__ entVal,
    const float* __restrict__ Wv1, const float* __restrict__ Wv2,
    const float* __restrict__ Wv3,
    float* Vn, float* __restrict__ tp0,
    int ntask, int base1, int C1, int base2, int C2, int base3, int C3, int tptot)
{
  __shared__ float As[256], Bs[256];
  __shared__ float tp[2496];
  const int e = blockIdx.x;
  const int tid = threadIdx.x;
  float ve = varepsp[0];
  float eps = rsqrtf(1.f + ve*ve);
  int s = senders[e];
  As[tid] = node[((size_t)s<<8) + tid] * eps;
  Bs[tid] = V[((size_t)e<<8) + tid];
  for (int i = tid; i < tptot; i += 256) tp[i] = 0.f;
  __syncthreads();
  for (int task = tid; task < ntask; task += 256) {
    int p = task >> 4, m = task & 15;
    int tpOff = pmeta[p*4+0] + m*pmeta[p*4+3];
    int es = pmeta[p*4+1], ec = pmeta[p*4+2];
    const float* Am = &As[m<<4];
    const float* Bm = &Bs[m<<4];
    float* out = &tp[tpOff];
    for (int t = 0; t < ec; t++) {
      int ijk = entIJK[es+t];
      float v = entVal[es+t];
      out[ijk>>16] += v * Am[ijk & 255] * Bm[(ijk>>8) & 255];
    }
  }
  __syncthreads();
  if (tid < 64) tp0[((size_t)e<<6) + tid] = tp[tid];
  const int d = tid & 15, kabs = tid >> 4;
  float outv = 0.f;
  if (kabs >= 1) {
    int base, C, kd, kloc; const float* Wv;
    if (kabs < 4)      { base=base1; C=C1; kd=3; kloc=kabs-1; Wv=Wv1; }
    else if (kabs < 9) { base=base2; C=C2; kd=5; kloc=kabs-4; Wv=Wv2; }
    else               { base=base3; C=C3; kd=7; kloc=kabs-9; Wv=Wv3; }
    float acc = 0.f;
    for (int c = 0; c < C; c++)
      acc += tp[base + c*kd + kloc] * Wv[(c<<4) + d];
    outv = acc * rsqrtf((float)C);
  }
  Vn[((size_t)e<<8) + (d<<4) + kabs] = outv;
}

// layer-2 TP: l3=0 only (paths 0..3 of the table), one thread per (e, p*16+m)
__global__ void tp2_k(const float* __restrict__ node, const float* __restrict__ Vn,
    const int* __restrict__ senders, const float* __restrict__ varepsp,
    const int* __restrict__ pmeta, const int* __restrict__ entIJK,
    const float* __restrict__ entVal, float* __restrict__ tp0)
{
  const int gid = blockIdx.x*256 + threadIdx.x;
  const int e = gid >> 6, c = gid & 63;
  const int p = c >> 4, m = c & 15;
  float ve = varepsp[0];
  float eps = rsqrtf(1.f + ve*ve);
  int s = senders[e];
  const float* Am = &node[((size_t)s<<8) + (m<<4)];
  const float* Bm = &Vn[((size_t)e<<8) + (m<<4)];
  int es = pmeta[p*4+1], ec = pmeta[p*4+2];
  float acc = 0.f;
  for (int t=0;t<ec;t++){
    int ijk = entIJK[es+t];
    acc += entVal[es+t] * Am[ijk&255] * Bm[(ijk>>8)&255];
  }
  tp0[((size_t)e<<6)+c] = acc * eps;
}

// out[e] = env[e] * dot(X[e,:128], Wout) / sqrt(128)
__global__ void final_k(const float* __restrict__ X, const float* __restrict__ Wout,
                        const float* __restrict__ env, float* __restrict__ out)
{
  const int e = blockIdx.x*256 + threadIdx.x;
  float acc = 0.f;
#pragma unroll 16
  for (int k=0;k<128;k++) acc += X[((size_t)e<<7)+k]*Wout[k];
  out[e] = env[e]*acc*0.088388347648318447f;
}

// ============================ host launcher ============================

static void launch_gemm(int flags, const float* A1, const float* A2, int K1, int K,
    const float* W, int N, float* C, const float* env, const float* alphap,
    const float* Xres, hipStream_t stream)
{
  dim3 grid(E_EDGES/64, (N+63)/64);
  switch(flags){
    case F_NONE:        gemm_k<F_NONE>       <<<grid,256,0,stream>>>(A1,A2,K1,K,W,N,C,env,alphap,Xres); break;
    case F_SILU:        gemm_k<F_SILU>       <<<grid,256,0,stream>>>(A1,A2,K1,K,W,N,C,env,alphap,Xres); break;
    case F_ENV:         gemm_k<F_ENV>        <<<grid,256,0,stream>>>(A1,A2,K1,K,W,N,C,env,alphap,Xres); break;
    case F_ENV|F_RESID: gemm_k<F_ENV|F_RESID><<<grid,256,0,stream>>>(A1,A2,K1,K,W,N,C,env,alphap,Xres); break;
  }
}

extern "C" void kernel_launch(void* const* d_in, const int* in_sizes, int n_in,
                              void* d_out, int out_size, void* d_ws, size_t ws_size,
                              hipStream_t stream)
{
  const float* vectors = (const float*)d_in[0];
  const float* vareps  = (const float*)d_in[1];
  const float* alpha   = (const float*)d_in[2];
  const float* emb     = (const float*)d_in[3];
  const float* W_tb1   = (const float*)d_in[4];
  const float* W_tb2   = (const float*)d_in[5];
  const float* W_tb3   = (const float*)d_in[6];
  const float* W_tb4   = (const float*)d_in[7];
  const float* W_w0    = (const float*)d_in[8];
  const float* W_w1    = (const float*)d_in[9];
  const float* W_l11   = (const float*)d_in[10];
  const float* W_l12   = (const float*)d_in[11];
  const float* W_l13   = (const float*)d_in[12];
  const float* W_v1    = (const float*)d_in[13];
  const float* W_v2    = (const float*)d_in[14];
  const float* W_v3    = (const float*)d_in[15];
  const float* W_w2    = (const float*)d_in[16];
  const float* W_l21   = (const float*)d_in[17];
  const float* W_l22   = (const float*)d_in[18];
  const float* W_l23   = (const float*)d_in[19];
  const float* W_h     = (const float*)d_in[20];
  const float* W_out   = (const float*)d_in[21];
  const int* senders   = (const int*)d_in[22];
  const int* receivers = (const int*)d_in[23];
  const int* species   = (const int*)d_in[24];

  // CG tables: recomputed each call into static storage (same values every
  // time — deterministic). Static so the host pointer recorded by the
  // captured hipMemcpyAsync nodes stays valid across graph replays.
  static cgt::Tables tb;
  cgt::build(tb);

  char* ws = (char*)d_ws;
  size_t off = 0;
  auto alloc = [&](size_t bytes)->void*{
    void* p = ws + off; off += (bytes + 255) & ~(size_t)255; return p;
  };
  float* t_val = (float*)alloc(sizeof(tb.val));
  int*   t_ijk = (int*)  alloc(sizeof(tb.ijk));
  int*   t_pm  = (int*)  alloc(sizeof(tb.pmeta));
  float* envb  = (float*)alloc((size_t)E_EDGES*4);
  float* Yb    = (float*)alloc((size_t)E_EDGES*16*4);
  float* xb    = (float*)alloc((size_t)E_EDGES*256*4);
  float* Vb    = (float*)alloc((size_t)E_EDGES*256*4);   // V, then Vn in-place
  float* bufA  = (float*)alloc((size_t)E_EDGES*256*4);
  float* bufB  = (float*)alloc((size_t)E_EDGES*256*4);
  float* tp0b  = (float*)alloc((size_t)E_EDGES*64*4);
  float* wb    = (float*)alloc((size_t)E_EDGES*16*4);
  float* nodeb = (float*)alloc((size_t)NNODES*256*4);
  if (off > ws_size) {
    fprintf(stderr, "[allegro] workspace too small: need %zu, have %zu\n", off, ws_size);
    return;
  }

  hipMemcpyAsync(t_val, tb.val,   sizeof(tb.val),   hipMemcpyHostToDevice, stream);
  hipMemcpyAsync(t_ijk, tb.ijk,   sizeof(tb.ijk),   hipMemcpyHostToDevice, stream);
  hipMemcpyAsync(t_pm,  tb.pmeta, sizeof(tb.pmeta), hipMemcpyHostToDevice, stream);

  const int ntask = tb.npaths * 16;
  const int b1 = tb.l3base[1], b2 = tb.l3base[2], b3 = tb.l3base[3];
  const int C1 = tb.l3np[1]*16, C2 = tb.l3np[2]*16, C3 = tb.l3np[3]*16;

  // 1. edge features + Y + env
  edge_init_k<<<E_EDGES/256, 256, 0, stream>>>(vectors, senders, receivers, species,
                                               emb, envb, Yb, bufA);
  // 2. two-body MLP: 72 -> 32 -> 64 -> 128 -> 256 (env on last)
  launch_gemm(F_SILU, bufA, nullptr, 72, 72,  W_tb1, 32,  bufB, envb, alpha, nullptr, stream);
  launch_gemm(F_SILU, bufB, nullptr, 32, 32,  W_tb2, 64,  bufA, envb, alpha, nullptr, stream);
  launch_gemm(F_SILU, bufA, nullptr, 64, 64,  W_tb3, 128, bufB, envb, alpha, nullptr, stream);
  launch_gemm(F_ENV,  bufB, nullptr, 128,128, W_tb4, 256, xb,   envb, alpha, nullptr, stream);
  // 3. V = dense(x,W_w0) outer Y
  dense16_k<<<E_EDGES/16, 256, 0, stream>>>(xb, W_w0, wb);
  vinit_k<<<E_EDGES, 256, 0, stream>>>(wb, Yb, Vb);

  // ---- layer 1 ----
  dense16_k<<<E_EDGES/16, 256, 0, stream>>>(xb, W_w1, wb);
  hipMemsetAsync(nodeb, 0, (size_t)NNODES*256*4, stream);
  scatter_k<<<E_EDGES, 256, 0, stream>>>(wb, Yb, senders, nodeb);
  tp1_k<<<E_EDGES, 256, 0, stream>>>(nodeb, Vb, senders, vareps, t_pm, t_ijk, t_val,
                                     W_v1, W_v2, W_v3, Vb, tp0b,
                                     ntask, b1, C1, b2, C2, b3, C3, tb.tptot);
  launch_gemm(F_SILU,        xb,   tp0b,   256, 320, W_l11, 256, bufB, envb, alpha, nullptr, stream);
  launch_gemm(F_SILU,        bufB, nullptr,256, 256, W_l12, 256, bufA, envb, alpha, nullptr, stream);
  launch_gemm(F_ENV|F_RESID, bufA, nullptr,256, 256, W_l13, 256, xb,   envb, alpha, xb,      stream);

  // ---- layer 2 (lmax_out = 0) ----
  dense16_k<<<E_EDGES/16, 256, 0, stream>>>(xb, W_w2, wb);
  hipMemsetAsync(nodeb, 0, (size_t)NNODES*256*4, stream);
  scatter_k<<<E_EDGES, 256, 0, stream>>>(wb, Yb, senders, nodeb);
  tp2_k<<<E_EDGES*64/256, 256, 0, stream>>>(nodeb, Vb, senders, vareps, t_pm, t_ijk,
                                            t_val, tp0b);
  launch_gemm(F_SILU,        xb,   tp0b,   256, 320, W_l21, 256, bufB, envb, alpha, nullptr, stream);
  launch_gemm(F_SILU,        bufB, nullptr,256, 256, W_l22, 256, bufA, envb, alpha, nullptr, stream);
  launch_gemm(F_ENV|F_RESID, bufA, nullptr,256, 256, W_l23, 256, xb,   envb, alpha, xb,      stream);

  // ---- head ----
  launch_gemm(F_NONE, xb, nullptr, 256, 256, W_h, 128, bufB, envb, alpha, nullptr, stream);
  final_k<<<E_EDGES/256, 256, 0, stream>>>(bufB, W_out, envb, (float*)d_out);
}

// Round 2
// 1279.579 us; speedup vs baseline: 1.1102x; 1.1102x over previous
//
#include <hip/hip_runtime.h>
#include <cmath>
#include <complex>
#include <cstdio>
#include <algorithm>

#define E_EDGES 32768
#define NNODES  2048

// ============================ host-side CG tables ============================
namespace cgt {

static double fct(int n){
  static const double f[13] = {1.,1.,2.,6.,24.,120.,720.,5040.,40320.,362880.,
                               3628800.,39916800.,479001600.};
  return f[n];
}

static double cg(int j1,int m1,int j2,int m2,int j3,int m3){
  if (m1+m2 != m3) return 0.0;
  double pre = std::sqrt((2*j3+1)*fct(j1+j2-j3)*fct(j1-j2+j3)*fct(-j1+j2+j3)/fct(j1+j2+j3+1));
  pre *= std::sqrt(fct(j3+m3)*fct(j3-m3)*fct(j1-m1)*fct(j1+m1)*fct(j2-m2)*fct(j2+m2));
  int kmin = 0;
  if (j2-j3-m1 > kmin) kmin = j2-j3-m1;
  if (j1-j3+m2 > kmin) kmin = j1-j3+m2;
  int kmax = j1+j2-j3;
  if (j1-m1 < kmax) kmax = j1-m1;
  if (j2+m2 < kmax) kmax = j2+m2;
  double s = 0.0;
  for (int k=kmin;k<=kmax;k++){
    double d = fct(k)*fct(j1+j2-j3-k)*fct(j1-m1-k)*fct(j2+m2-k)*fct(j3-j2+m1+k)*fct(j3-j1-m2+k);
    s += ((k&1)? -1.0:1.0)/d;
  }
  return pre*s;
}

typedef std::complex<double> cd;

static void umat(int l, cd U[7][7]){
  for (int a=0;a<7;a++) for (int b=0;b<7;b++) U[a][b]=cd(0,0);
  U[l][l] = cd(1,0);
  double s2 = 1.0/std::sqrt(2.0);
  for (int m=1;m<=l;m++){
    double sg = (m&1)? -1.0 : 1.0;
    U[l+m][l-m] = cd(s2,0);
    U[l+m][l+m] = cd(sg*s2,0);
    U[l-m][l-m] = cd(0, s2);
    U[l-m][l+m] = cd(0, -sg*s2);
  }
}

static bool realCoupling(int l1,int l2,int l3, double T[7][7][7]){
  cd U1[7][7],U2[7][7],U3[7][7];
  umat(l1,U1); umat(l2,U2); umat(l3,U3);
  int n1=2*l1+1, n2=2*l2+1, n3=2*l3+1;
  double Cg[7][7][7];
  for (int m=0;m<n1;m++) for(int n=0;n<n2;n++) for(int k=0;k<n3;k++)
    Cg[m][n][k] = cg(l1,m-l1,l2,n-l2,l3,k-l3);
  double Tr[7][7][7], Ti[7][7][7];
  double nr=0, ni=0;
  for (int a=0;a<n1;a++) for(int b=0;b<n2;b++) for(int c=0;c<n3;c++){
    cd s(0,0);
    for (int m=0;m<n1;m++){
      if (U1[a][m]==cd(0,0)) continue;
      for (int n=0;n<n2;n++){
        if (U2[b][n]==cd(0,0)) continue;
        for (int k=0;k<n3;k++){
          double cgv = Cg[m][n][k];
          if (cgv==0.0) continue;
          s += U1[a][m]*U2[b][n]*std::conj(U3[c][k])*cgv;
        }
      }
    }
    Tr[a][b][c]=s.real(); Ti[a][b][c]=s.imag();
    nr += s.real()*s.real(); ni += s.imag()*s.imag();
  }
  bool useR = (nr >= ni);
  double nn = std::sqrt(useR? nr : ni);
  if (nn < 1e-8) return false;
  for (int a=0;a<n1;a++)for(int b=0;b<n2;b++)for(int c=0;c<n3;c++)
    T[a][b][c] = (useR? Tr[a][b][c] : Ti[a][b][c])/nn;
  return true;
}

struct Tables {
  float val[4096];
  int   ij[4096];        // (a_abs) | (b_abs<<8), entries grouped by (path, c)
  int   pmeta[40*4];     // per SLOT: tpOff(orig layout), entStart, entCount, kdim
  int   ccnt[40*8];      // per SLOT: entry count for each c (kd <= 7)
  int   l3base[4];
  int   l3np[4];
  int   npaths;
  int   nent;
  int   tptot;
};

struct PathTmp {
  int l1,l2,l3, tpoff, kd;
  int ec;                 // total nonzero entries
  double T[7][7][7];
};

static void build(Tables& tb){
  static PathTmp paths[40];
  int np = 0, tpoff = 0;
  int l3start[5];
  for (int l3=0;l3<=3;l3++){
    tb.l3base[l3] = tpoff;
    l3start[l3] = np;
    int kd = 2*l3+1;
    for (int l1=0;l1<=3;l1++) for (int l2=0;l2<=3;l2++){
      int lo = (l1>l2)? l1-l2 : l2-l1;
      int hi = std::min(l1+l2,3);
      if (l3 < lo || l3 > hi) continue;
      PathTmp& pt = paths[np];
      if (!realCoupling(l1,l2,l3,pt.T)) continue;
      pt.l1=l1; pt.l2=l2; pt.l3=l3; pt.kd=kd; pt.tpoff=tpoff;
      double scale = std::sqrt((double)kd);
      int cnt = 0;
      for (int a=0;a<2*l1+1;a++)for(int b=0;b<2*l2+1;b++)for(int c=0;c<kd;c++)
        if (std::fabs(pt.T[a][b][c]*scale) > 1e-7) cnt++;
      pt.ec = cnt;
      tpoff += 16*kd;
      np++;
    }
  }
  l3start[4] = np;
  for (int l3=0;l3<=3;l3++) tb.l3np[l3] = l3start[l3+1]-l3start[l3];
  // sort slots within each l3 block by entry count descending (divergence/balance)
  static int order[40];
  for (int i=0;i<np;i++) order[i]=i;
  for (int l3=0;l3<=3;l3++)
    std::sort(order+l3start[l3], order+l3start[l3+1],
              [&](int a,int b){ return paths[a].ec > paths[b].ec; });
  // emit entries grouped by (slot, c)
  int ep = 0;
  for (int slot=0; slot<np; slot++){
    const PathTmp& pt = paths[order[slot]];
    double scale = std::sqrt((double)pt.kd);
    int s1 = pt.l1*pt.l1, s2 = pt.l2*pt.l2;
    tb.pmeta[slot*4+0] = pt.tpoff;
    tb.pmeta[slot*4+1] = ep;
    int tot = 0;
    for (int c=0;c<pt.kd;c++){
      int cnt = 0;
      for (int a=0;a<2*pt.l1+1;a++)for(int b=0;b<2*pt.l2+1;b++){
        double v = pt.T[a][b][c]*scale;
        if (std::fabs(v) > 1e-7){
          tb.val[ep] = (float)v;
          tb.ij[ep]  = (s1+a) | ((s2+b)<<8);
          ep++; cnt++;
        }
      }
      tb.ccnt[slot*8+c] = cnt;
      tot += cnt;
    }
    for (int c=pt.kd;c<8;c++) tb.ccnt[slot*8+c]=0;
    tb.pmeta[slot*4+2] = tot;
    tb.pmeta[slot*4+3] = pt.kd;
  }
  tb.npaths = np; tb.nent = ep; tb.tptot = tpoff;
}

} // namespace cgt

// ============================ device kernels ============================

enum GFlags { F_NONE=0, F_SILU=1, F_ENV=2, F_RESID=4 };

// Generic tiled GEMM: C[M,N] = post( A[M,K] @ W[K,N] / sqrt(K) )
// A is split-source: cols [0,K1) from A1 (stride K1), cols [K1,K) from A2 (stride K-K1).
template<int FLAGS>
__global__ __launch_bounds__(256) void gemm_k(
    const float* __restrict__ A1, const float* __restrict__ A2,
    int K1, int K, const float* __restrict__ W, int N,
    float* Cout,
    const float* __restrict__ env, const float* __restrict__ alphap,
    const float* Xres)
{
  __shared__ float As[16][68];
  __shared__ float Ws[16][68];
  const int tid = threadIdx.x;
  const int bm = blockIdx.x * 64;
  const int bn = blockIdx.y * 64;
  const int tx = tid & 15, ty = tid >> 4;
  const int K2 = K - K1;
  float acc[4][4] = {};
  for (int k0 = 0; k0 < K; k0 += 16) {
#pragma unroll
    for (int i = 0; i < 4; i++) {
      int idx = tid + i*256;
      int m = idx >> 4, kk = idx & 15;
      int k = k0 + kk;
      float v = 0.f;
      if (k < K) {
        int row = bm + m;
        v = (k < K1) ? A1[(size_t)row*K1 + k] : A2[(size_t)row*K2 + (k-K1)];
      }
      As[kk][m] = v;
    }
#pragma unroll
    for (int i = 0; i < 4; i++) {
      int idx = tid + i*256;
      int n = idx & 63, kk = idx >> 6;
      int k = k0 + kk, col = bn + n;
      Ws[kk][n] = (k < K && col < N) ? W[(size_t)k*N + col] : 0.f;
    }
    __syncthreads();
#pragma unroll
    for (int kk = 0; kk < 16; kk++) {
      float a[4], b[4];
#pragma unroll
      for (int i=0;i<4;i++) a[i] = As[kk][ty*4+i];
#pragma unroll
      for (int j=0;j<4;j++) b[j] = Ws[kk][tx*4+j];
#pragma unroll
      for (int i=0;i<4;i++)
#pragma unroll
        for (int j=0;j<4;j++)
          acc[i][j] += a[i]*b[j];
    }
    __syncthreads();
  }
  const float rscale = 1.f/sqrtf((float)K);
  float a2 = 0.f, inv1a2 = 1.f;
  if (FLAGS & F_RESID) { float al = alphap[0]; a2 = al*al; inv1a2 = 1.f/(1.f+a2); }
#pragma unroll
  for (int i=0;i<4;i++) {
    int row = bm + ty*4 + i;
    float ev = (FLAGS & F_ENV) ? env[row] : 1.f;
#pragma unroll
    for (int j=0;j<4;j++) {
      int col = bn + tx*4 + j;
      if (col >= N) continue;
      float v = acc[i][j]*rscale;
      if (FLAGS & F_SILU) v = v/(1.f+__expf(-v));
      if (FLAGS & F_ENV)  v *= ev;
      if (FLAGS & F_RESID) v = (Xres[(size_t)row*N+col] + a2*v)*inv1a2;
      Cout[(size_t)row*N+col] = v;
    }
  }
}

// dense to 16 outputs, K=256 fixed, scale 1/16, no activation
__global__ __launch_bounds__(256) void dense16_k(const float* __restrict__ A,
    const float* __restrict__ W, float* __restrict__ C)
{
  __shared__ float As[16*256];
  const int r0 = blockIdx.x << 4;
  const int tid = threadIdx.x;
  for (int i = tid; i < 16*256; i += 256)
    As[i] = A[((size_t)r0<<8) + i];
  __syncthreads();
  const int r = tid >> 4, n = tid & 15;
  float acc = 0.f;
#pragma unroll 8
  for (int k = 0; k < 256; k++)
    acc += As[(r<<8)+k] * W[(k<<4)+n];
  C[((size_t)(r0+r)<<4)+n] = acc * 0.0625f;
}

__global__ void edge_init_k(const float* __restrict__ vectors, const int* __restrict__ senders,
    const int* __restrict__ receivers, const int* __restrict__ species,
    const float* __restrict__ emb, float* __restrict__ envb, float* __restrict__ Yb,
    float* __restrict__ x72)
{
  const int e = blockIdx.x*256 + threadIdx.x;
  float vx = vectors[e*3+0], vy = vectors[e*3+1], vz = vectors[e*3+2];
  float d = sqrtf(vx*vx+vy*vy+vz*vz);
  float dd = (d==0.f) ? 1.f : d;
  float invd = 1.f/dd;
  float x = vx*invd, y = vy*invd, z = vz*invd;
  float d2=d*d, d3=d2*d, d6=d3*d3, d7=d6*d, d8=d7*d;
  float envv = (d<1.f) ? (1.f - 28.f*d6 + 48.f*d7 - 21.f*d8) : 0.f;
  envb[e] = envv;
  float mask = (d==0.f)?0.f:1.f;
  const float SQ2 = 1.41421356237309515f;
  const float PIf = 3.14159265358979323846f;
  float* xr = x72 + (size_t)e*72;
#pragma unroll
  for (int n=1;n<=8;n++)
    xr[n-1] = SQ2 * sinf((float)n*PIf*dd)*invd*envv*mask;
  int sp_s = species[senders[e]], sp_r = species[receivers[e]];
  const float* es_ = emb + (size_t)sp_s*32;
  const float* er_ = emb + (size_t)sp_r*32;
#pragma unroll 8
  for (int k=0;k<32;k++){ xr[8+k] = es_[k]*mask; xr[40+k] = er_[k]*mask; }
  // real spherical harmonics up to l=3
  float x2=x*x, y2=y*y, z2=z*z;
  const float s3=1.7320508075688772f, s15=3.872983346207417f, s5=2.23606797749979f;
  const float s358=2.0916500663351889f, s105=10.246950765959598f;
  const float s218=1.6201851746019651f, s7=2.6457513110645907f;
  float* Yr = Yb + ((size_t)e<<4);
  Yr[0]=1.f;           Yr[1]=s3*y;          Yr[2]=s3*z;           Yr[3]=s3*x;
  Yr[4]=s15*x*y;       Yr[5]=s15*y*z;       Yr[6]=0.5f*s5*(3.f*z2-1.f);
  Yr[7]=s15*x*z;       Yr[8]=0.5f*s15*(x2-y2);
  Yr[9]=s358*y*(3.f*x2-y2);  Yr[10]=s105*x*y*z;  Yr[11]=s218*y*(5.f*z2-1.f);
  Yr[12]=0.5f*s7*(5.f*z2-3.f)*z;  Yr[13]=s218*x*(5.f*z2-1.f);
  Yr[14]=0.5f*s105*(x2-y2)*z;     Yr[15]=s358*x*(x2-y2);
}

// V[e,m,k] = w0[e,m]*Y[e,k]
__global__ void vinit_k(const float* __restrict__ w0, const float* __restrict__ Y,
                        float* __restrict__ V)
{
  const int gid = blockIdx.x*256 + threadIdx.x;
  const int e = gid >> 8, idx = gid & 255;
  V[gid] = w0[(e<<4)+(idx>>4)] * Y[(e<<4)+(idx&15)];
}

// node[senders[e], m, k] += w[e,m]*Y[e,k]
__global__ void scatter_k(const float* __restrict__ w, const float* __restrict__ Y,
                          const int* __restrict__ senders, float* node)
{
  const int gid = blockIdx.x*256 + threadIdx.x;
  const int e = gid >> 8, idx = gid & 255;
  float v = w[(e<<4) + (idx>>4)] * Y[(e<<4) + (idx&15)];
  atomicAdd(&node[((size_t)senders[e]<<8) + idx], v);
}

// layer-1 TP: full tensor product into LDS, then dense_axis -> Vn, plus tp0 out.
// Operands staged TRANSPOSED + padded (As[a*17+m]) so the 16 lanes of a
// path-group (same entry, different m) read consecutive LDS words -> no bank
// conflicts. Entries grouped by (path, c) on host so accumulation is a scalar
// register; tp written exactly once per slot (no zero-init, no RMW).
__global__ __launch_bounds__(256) void tp1_k(
    const float* __restrict__ node, const float* V,
    const int* __restrict__ senders, const float* __restrict__ varepsp,
    const int* __restrict__ pmeta, const int* __restrict__ ccnt,
    const int* __restrict__ entIJ, const float* __restrict__ entVal,
    const float* __restrict__ Wv1, const float* __restrict__ Wv2,
    const float* __restrict__ Wv3,
    float* Vn, float* __restrict__ tp0,
    int ntask, int base1, int C1, int base2, int C2, int base3, int C3)
{
  __shared__ float As[16*17], Bs[16*17];
  __shared__ float tp[2496];
  const int e = blockIdx.x;
  const int tid = threadIdx.x;
  float ve = varepsp[0];
  float eps = rsqrtf(1.f + ve*ve);
  int s = senders[e];
  {
    float av = node[((size_t)s<<8) + tid] * eps;
    float bv = V[((size_t)e<<8) + tid];
    int m = tid >> 4, a = tid & 15;
    As[a*17+m] = av;
    Bs[a*17+m] = bv;
  }
  __syncthreads();
  for (int task = tid; task < ntask; task += 256) {
    int p = task >> 4, m = task & 15;
    int kd    = pmeta[p*4+3];
    int tpOff = pmeta[p*4+0] + m*kd;
    int t     = pmeta[p*4+1];
    for (int c = 0; c < kd; c++) {
      int cnt = ccnt[p*8+c];
      float acc = 0.f;
      for (int i = 0; i < cnt; i++, t++) {
        int ij = entIJ[t];
        acc += entVal[t] * As[(ij&255)*17+m] * Bs[((ij>>8)&255)*17+m];
      }
      tp[tpOff + c] = acc;
    }
  }
  __syncthreads();
  if (tid < 64) tp0[((size_t)e<<6) + tid] = tp[tid];
  const int d = tid & 15, kabs = tid >> 4;
  float outv = 0.f;
  if (kabs >= 1) {
    int base, C, kd, kloc; const float* Wv;
    if (kabs < 4)      { base=base1; C=C1; kd=3; kloc=kabs-1; Wv=Wv1; }
    else if (kabs < 9) { base=base2; C=C2; kd=5; kloc=kabs-4; Wv=Wv2; }
    else               { base=base3; C=C3; kd=7; kloc=kabs-9; Wv=Wv3; }
    float acc = 0.f;
    for (int c = 0; c < C; c++)
      acc += tp[base + c*kd + kloc] * Wv[(c<<4) + d];
    outv = acc * rsqrtf((float)C);
  }
  Vn[((size_t)e<<8) + (d<<4) + kabs] = outv;
}

// layer-2 TP: l3=0 only (slots 0..3 of the table), one thread per (e, p*16+m).
// Write index uses the slot's tpOff so output column order matches weights.
__global__ void tp2_k(const float* __restrict__ node, const float* __restrict__ Vn,
    const int* __restrict__ senders, const float* __restrict__ varepsp,
    const int* __restrict__ pmeta, const int* __restrict__ entIJ,
    const float* __restrict__ entVal, float* __restrict__ tp0)
{
  const int gid = blockIdx.x*256 + threadIdx.x;
  const int e = gid >> 6, c = gid & 63;
  const int p = c >> 4, m = c & 15;
  float ve = varepsp[0];
  float eps = rsqrtf(1.f + ve*ve);
  int s = senders[e];
  const float* Am = &node[((size_t)s<<8) + (m<<4)];
  const float* Bm = &Vn[((size_t)e<<8) + (m<<4)];
  int es = pmeta[p*4+1], ec = pmeta[p*4+2];
  float acc = 0.f;
  for (int t=0;t<ec;t++){
    int ij = entIJ[es+t];
    acc += entVal[es+t] * Am[ij&255] * Bm[(ij>>8)&255];
  }
  tp0[((size_t)e<<6) + pmeta[p*4+0] + m] = acc * eps;
}

// out[e] = env[e] * dot(X[e,:128], Wout) / sqrt(128)
__global__ void final_k(const float* __restrict__ X, const float* __restrict__ Wout,
                        const float* __restrict__ env, float* __restrict__ out)
{
  const int e = blockIdx.x*256 + threadIdx.x;
  float acc = 0.f;
#pragma unroll 16
  for (int k=0;k<128;k++) acc += X[((size_t)e<<7)+k]*Wout[k];
  out[e] = env[e]*acc*0.088388347648318447f;
}

// ============================ host launcher ============================

static void launch_gemm(int flags, const float* A1, const float* A2, int K1, int K,
    const float* W, int N, float* C, const float* env, const float* alphap,
    const float* Xres, hipStream_t stream)
{
  dim3 grid(E_EDGES/64, (N+63)/64);
  switch(flags){
    case F_NONE:        gemm_k<F_NONE>       <<<grid,256,0,stream>>>(A1,A2,K1,K,W,N,C,env,alphap,Xres); break;
    case F_SILU:        gemm_k<F_SILU>       <<<grid,256,0,stream>>>(A1,A2,K1,K,W,N,C,env,alphap,Xres); break;
    case F_ENV:         gemm_k<F_ENV>        <<<grid,256,0,stream>>>(A1,A2,K1,K,W,N,C,env,alphap,Xres); break;
    case F_ENV|F_RESID: gemm_k<F_ENV|F_RESID><<<grid,256,0,stream>>>(A1,A2,K1,K,W,N,C,env,alphap,Xres); break;
  }
}

extern "C" void kernel_launch(void* const* d_in, const int* in_sizes, int n_in,
                              void* d_out, int out_size, void* d_ws, size_t ws_size,
                              hipStream_t stream)
{
  const float* vectors = (const float*)d_in[0];
  const float* vareps  = (const float*)d_in[1];
  const float* alpha   = (const float*)d_in[2];
  const float* emb     = (const float*)d_in[3];
  const float* W_tb1   = (const float*)d_in[4];
  const float* W_tb2   = (const float*)d_in[5];
  const float* W_tb3   = (const float*)d_in[6];
  const float* W_tb4   = (const float*)d_in[7];
  const float* W_w0    = (const float*)d_in[8];
  const float* W_w1    = (const float*)d_in[9];
  const float* W_l11   = (const float*)d_in[10];
  const float* W_l12   = (const float*)d_in[11];
  const float* W_l13   = (const float*)d_in[12];
  const float* W_v1    = (const float*)d_in[13];
  const float* W_v2    = (const float*)d_in[14];
  const float* W_v3    = (const float*)d_in[15];
  const float* W_w2    = (const float*)d_in[16];
  const float* W_l21   = (const float*)d_in[17];
  const float* W_l22   = (const float*)d_in[18];
  const float* W_l23   = (const float*)d_in[19];
  const float* W_h     = (const float*)d_in[20];
  const float* W_out   = (const float*)d_in[21];
  const int* senders   = (const int*)d_in[22];
  const int* receivers = (const int*)d_in[23];
  const int* species   = (const int*)d_in[24];

  // CG tables: recomputed each call into static storage (same values every
  // time — deterministic). Static so the host pointer recorded by the
  // captured hipMemcpyAsync nodes stays valid across graph replays.
  static cgt::Tables tb;
  cgt::build(tb);

  char* ws = (char*)d_ws;
  size_t off = 0;
  auto alloc = [&](size_t bytes)->void*{
    void* p = ws + off; off += (bytes + 255) & ~(size_t)255; return p;
  };
  float* t_val = (float*)alloc(sizeof(tb.val));
  int*   t_ij  = (int*)  alloc(sizeof(tb.ij));
  int*   t_pm  = (int*)  alloc(sizeof(tb.pmeta));
  int*   t_cc  = (int*)  alloc(sizeof(tb.ccnt));
  float* envb  = (float*)alloc((size_t)E_EDGES*4);
  float* Yb    = (float*)alloc((size_t)E_EDGES*16*4);
  float* xb    = (float*)alloc((size_t)E_EDGES*256*4);
  float* Vb    = (float*)alloc((size_t)E_EDGES*256*4);   // V, then Vn in-place
  float* bufA  = (float*)alloc((size_t)E_EDGES*256*4);
  float* bufB  = (float*)alloc((size_t)E_EDGES*256*4);
  float* tp0b  = (float*)alloc((size_t)E_EDGES*64*4);
  float* wb    = (float*)alloc((size_t)E_EDGES*16*4);
  float* nodeb = (float*)alloc((size_t)NNODES*256*4);
  if (off > ws_size) {
    fprintf(stderr, "[allegro] workspace too small: need %zu, have %zu\n", off, ws_size);
    return;
  }

  hipMemcpyAsync(t_val, tb.val,   sizeof(tb.val),   hipMemcpyHostToDevice, stream);
  hipMemcpyAsync(t_ij,  tb.ij,    sizeof(tb.ij),    hipMemcpyHostToDevice, stream);
  hipMemcpyAsync(t_pm,  tb.pmeta, sizeof(tb.pmeta), hipMemcpyHostToDevice, stream);
  hipMemcpyAsync(t_cc,  tb.ccnt,  sizeof(tb.ccnt),  hipMemcpyHostToDevice, stream);

  const int ntask = tb.npaths * 16;
  const int b1 = tb.l3base[1], b2 = tb.l3base[2], b3 = tb.l3base[3];
  const int C1 = tb.l3np[1]*16, C2 = tb.l3np[2]*16, C3 = tb.l3np[3]*16;

  // 1. edge features + Y + env
  edge_init_k<<<E_EDGES/256, 256, 0, stream>>>(vectors, senders, receivers, species,
                                               emb, envb, Yb, bufA);
  // 2. two-body MLP: 72 -> 32 -> 64 -> 128 -> 256 (env on last)
  launch_gemm(F_SILU, bufA, nullptr, 72, 72,  W_tb1, 32,  bufB, envb, alpha, nullptr, stream);
  launch_gemm(F_SILU, bufB, nullptr, 32, 32,  W_tb2, 64,  bufA, envb, alpha, nullptr, stream);
  launch_gemm(F_SILU, bufA, nullptr, 64, 64,  W_tb3, 128, bufB, envb, alpha, nullptr, stream);
  launch_gemm(F_ENV,  bufB, nullptr, 128,128, W_tb4, 256, xb,   envb, alpha, nullptr, stream);
  // 3. V = dense(x,W_w0) outer Y
  dense16_k<<<E_EDGES/16, 256, 0, stream>>>(xb, W_w0, wb);
  vinit_k<<<E_EDGES, 256, 0, stream>>>(wb, Yb, Vb);

  // ---- layer 1 ----
  dense16_k<<<E_EDGES/16, 256, 0, stream>>>(xb, W_w1, wb);
  hipMemsetAsync(nodeb, 0, (size_t)NNODES*256*4, stream);
  scatter_k<<<E_EDGES, 256, 0, stream>>>(wb, Yb, senders, nodeb);
  tp1_k<<<E_EDGES, 256, 0, stream>>>(nodeb, Vb, senders, vareps, t_pm, t_cc, t_ij, t_val,
                                     W_v1, W_v2, W_v3, Vb, tp0b,
                                     ntask, b1, C1, b2, C2, b3, C3);
  launch_gemm(F_SILU,        xb,   tp0b,   256, 320, W_l11, 256, bufB, envb, alpha, nullptr, stream);
  launch_gemm(F_SILU,        bufB, nullptr,256, 256, W_l12, 256, bufA, envb, alpha, nullptr, stream);
  launch_gemm(F_ENV|F_RESID, bufA, nullptr,256, 256, W_l13, 256, xb,   envb, alpha, xb,      stream);

  // ---- layer 2 (lmax_out = 0) ----
  dense16_k<<<E_EDGES/16, 256, 0, stream>>>(xb, W_w2, wb);
  hipMemsetAsync(nodeb, 0, (size_t)NNODES*256*4, stream);
  scatter_k<<<E_EDGES, 256, 0, stream>>>(wb, Yb, senders, nodeb);
  tp2_k<<<E_EDGES*64/256, 256, 0, stream>>>(nodeb, Vb, senders, vareps, t_pm, t_ij,
                                            t_val, tp0b);
  launch_gemm(F_SILU,        xb,   tp0b,   256, 320, W_l21, 256, bufB, envb, alpha, nullptr, stream);
  launch_gemm(F_SILU,        bufB, nullptr,256, 256, W_l22, 256, bufA, envb, alpha, nullptr, stream);
  launch_gemm(F_ENV|F_RESID, bufA, nullptr,256, 256, W_l23, 256, xb,   envb, alpha, xb,      stream);

  // ---- head ----
  launch_gemm(F_NONE, xb, nullptr, 256, 256, W_h, 128, bufB, envb, alpha, nullptr, stream);
  final_k<<<E_EDGES/256, 256, 0, stream>>>(bufB, W_out, envb, (float*)d_out);
}

// Round 3
// 776.060 us; speedup vs baseline: 1.8305x; 1.6488x over previous
//
#include <hip/hip_runtime.h>
#include <cmath>
#include <complex>
#include <cstdio>
#include <algorithm>

#define E_EDGES 32768
#define NNODES  2048

// ============================ host-side CG tables ============================
namespace cgt {

static double fct(int n){
  static const double f[13] = {1.,1.,2.,6.,24.,120.,720.,5040.,40320.,362880.,
                               3628800.,39916800.,479001600.};
  return f[n];
}

static double cg(int j1,int m1,int j2,int m2,int j3,int m3){
  if (m1+m2 != m3) return 0.0;
  double pre = std::sqrt((2*j3+1)*fct(j1+j2-j3)*fct(j1-j2+j3)*fct(-j1+j2+j3)/fct(j1+j2+j3+1));
  pre *= std::sqrt(fct(j3+m3)*fct(j3-m3)*fct(j1-m1)*fct(j1+m1)*fct(j2-m2)*fct(j2+m2));
  int kmin = 0;
  if (j2-j3-m1 > kmin) kmin = j2-j3-m1;
  if (j1-j3+m2 > kmin) kmin = j1-j3+m2;
  int kmax = j1+j2-j3;
  if (j1-m1 < kmax) kmax = j1-m1;
  if (j2+m2 < kmax) kmax = j2+m2;
  double s = 0.0;
  for (int k=kmin;k<=kmax;k++){
    double d = fct(k)*fct(j1+j2-j3-k)*fct(j1-m1-k)*fct(j2+m2-k)*fct(j3-j2+m1+k)*fct(j3-j1-m2+k);
    s += ((k&1)? -1.0:1.0)/d;
  }
  return pre*s;
}

typedef std::complex<double> cd;

static void umat(int l, cd U[7][7]){
  for (int a=0;a<7;a++) for (int b=0;b<7;b++) U[a][b]=cd(0,0);
  U[l][l] = cd(1,0);
  double s2 = 1.0/std::sqrt(2.0);
  for (int m=1;m<=l;m++){
    double sg = (m&1)? -1.0 : 1.0;
    U[l+m][l-m] = cd(s2,0);
    U[l+m][l+m] = cd(sg*s2,0);
    U[l-m][l-m] = cd(0, s2);
    U[l-m][l+m] = cd(0, -sg*s2);
  }
}

static bool realCoupling(int l1,int l2,int l3, double T[7][7][7]){
  cd U1[7][7],U2[7][7],U3[7][7];
  umat(l1,U1); umat(l2,U2); umat(l3,U3);
  int n1=2*l1+1, n2=2*l2+1, n3=2*l3+1;
  double Cg[7][7][7];
  for (int m=0;m<n1;m++) for(int n=0;n<n2;n++) for(int k=0;k<n3;k++)
    Cg[m][n][k] = cg(l1,m-l1,l2,n-l2,l3,k-l3);
  double Tr[7][7][7], Ti[7][7][7];
  double nr=0, ni=0;
  for (int a=0;a<n1;a++) for(int b=0;b<n2;b++) for(int c=0;c<n3;c++){
    cd s(0,0);
    for (int m=0;m<n1;m++){
      if (U1[a][m]==cd(0,0)) continue;
      for (int n=0;n<n2;n++){
        if (U2[b][n]==cd(0,0)) continue;
        for (int k=0;k<n3;k++){
          double cgv = Cg[m][n][k];
          if (cgv==0.0) continue;
          s += U1[a][m]*U2[b][n]*std::conj(U3[c][k])*cgv;
        }
      }
    }
    Tr[a][b][c]=s.real(); Ti[a][b][c]=s.imag();
    nr += s.real()*s.real(); ni += s.imag()*s.imag();
  }
  bool useR = (nr >= ni);
  double nn = std::sqrt(useR? nr : ni);
  if (nn < 1e-8) return false;
  for (int a=0;a<n1;a++)for(int b=0;b<n2;b++)for(int c=0;c<n3;c++)
    T[a][b][c] = (useR? Tr[a][b][c] : Ti[a][b][c])/nn;
  return true;
}

struct Tables {
  float val[4096];
  int   ij[4096];        // (a_abs) | (b_abs<<8), entries grouped by (path, c)
  int   pmeta[40*4];     // per SLOT: tpOff(orig layout), entStart, entCount, kdim
  int   ccnt[40*8];      // per SLOT: entry count for each c (kd <= 7)
  int   l3base[4];
  int   l3np[4];
  int   npaths;
  int   nent;
  int   tptot;
};

struct PathTmp {
  int l1,l2,l3, tpoff, kd;
  int ec;                 // total nonzero entries
  double T[7][7][7];
};

static void build(Tables& tb){
  static PathTmp paths[40];
  int np = 0, tpoff = 0;
  int l3start[5];
  for (int l3=0;l3<=3;l3++){
    tb.l3base[l3] = tpoff;
    l3start[l3] = np;
    int kd = 2*l3+1;
    for (int l1=0;l1<=3;l1++) for (int l2=0;l2<=3;l2++){
      int lo = (l1>l2)? l1-l2 : l2-l1;
      int hi = std::min(l1+l2,3);
      if (l3 < lo || l3 > hi) continue;
      PathTmp& pt = paths[np];
      if (!realCoupling(l1,l2,l3,pt.T)) continue;
      pt.l1=l1; pt.l2=l2; pt.l3=l3; pt.kd=kd; pt.tpoff=tpoff;
      double scale = std::sqrt((double)kd);
      int cnt = 0;
      for (int a=0;a<2*l1+1;a++)for(int b=0;b<2*l2+1;b++)for(int c=0;c<kd;c++)
        if (std::fabs(pt.T[a][b][c]*scale) > 1e-7) cnt++;
      pt.ec = cnt;
      tpoff += 16*kd;
      np++;
    }
  }
  l3start[4] = np;
  for (int l3=0;l3<=3;l3++) tb.l3np[l3] = l3start[l3+1]-l3start[l3];
  // sort slots within each l3 block by entry count descending (divergence/balance)
  static int order[40];
  for (int i=0;i<np;i++) order[i]=i;
  for (int l3=0;l3<=3;l3++)
    std::sort(order+l3start[l3], order+l3start[l3+1],
              [&](int a,int b){ return paths[a].ec > paths[b].ec; });
  // emit entries grouped by (slot, c)
  int ep = 0;
  for (int slot=0; slot<np; slot++){
    const PathTmp& pt = paths[order[slot]];
    double scale = std::sqrt((double)pt.kd);
    int s1 = pt.l1*pt.l1, s2 = pt.l2*pt.l2;
    tb.pmeta[slot*4+0] = pt.tpoff;
    tb.pmeta[slot*4+1] = ep;
    int tot = 0;
    for (int c=0;c<pt.kd;c++){
      int cnt = 0;
      for (int a=0;a<2*pt.l1+1;a++)for(int b=0;b<2*pt.l2+1;b++){
        double v = pt.T[a][b][c]*scale;
        if (std::fabs(v) > 1e-7){
          tb.val[ep] = (float)v;
          tb.ij[ep]  = (s1+a) | ((s2+b)<<8);
          ep++; cnt++;
        }
      }
      tb.ccnt[slot*8+c] = cnt;
      tot += cnt;
    }
    for (int c=pt.kd;c<8;c++) tb.ccnt[slot*8+c]=0;
    tb.pmeta[slot*4+2] = tot;
    tb.pmeta[slot*4+3] = pt.kd;
  }
  tb.npaths = np; tb.nent = ep; tb.tptot = tpoff;
}

} // namespace cgt

// ============================ device kernels ============================

enum GFlags { F_NONE=0, F_SILU=1, F_ENV=2, F_RESID=4 };

typedef __attribute__((ext_vector_type(8))) short bf16x8;
typedef __attribute__((ext_vector_type(4))) float f32x4;

__device__ inline unsigned short f2b(float f){
  union { float f; unsigned u; } x; x.f = f;
  unsigned r = (x.u + 0x7fffu + ((x.u >> 16) & 1u)) >> 16;
  return (unsigned short)r;
}

// XOR swizzle for 64B-row LDS tiles of bf16: spreads 16B units of 8
// consecutive rows over 8 distinct bank groups -> 2-way (free) on
// ds_read_b128 fragment loads. kh in ushort units (multiple of 4).
__device__ inline int swz(int row, int kh){
  int b = row*64 + kh*2;
  return b ^ (((row >> 1) & 3) << 4);
}

// ---- bf16 MFMA GEMM: C[M,N] = post( A[M,K] @ W[K,N] / sqrt(K) ) ----
// A fp32 (split-source like gemm_k), W pre-converted to bf16 TRANSPOSED
// Wt[N][K]. Tiles 128x128, BK=32, 4 waves (2x2), each wave 4x4 frags of
// 16x16x32. acc fp32 (MFMA native).
template<int FLAGS>
__global__ __launch_bounds__(256) void mgemm_k(
    const float* __restrict__ A1, const float* __restrict__ A2,
    int K1, int K, const unsigned short* __restrict__ Wt, int N,
    float* Cout, const float* __restrict__ env,
    const float* __restrict__ alphap, const float* Xres)
{
  __shared__ unsigned short AsB[128*32];
  __shared__ unsigned short BsB[128*32];
  const int tid  = threadIdx.x;
  const int wave = tid >> 6, lane = tid & 63;
  const int bm = blockIdx.x*128, bn = blockIdx.y*128;
  const int wr = (wave >> 1)*64, wc = (wave & 1)*64;
  const int K2 = K - K1;
  f32x4 acc[4][4] = {};

  const int sr  = tid >> 3;          // staging row 0..31 (A)
  const int skq = (tid & 7) * 4;     // staging k 0..28 step 4 (A)
  const int bn_ = tid >> 1;          // staging n 0..127 (B)
  const int bkh = (tid & 1) * 16;    // staging k half (B)

  for (int k0 = 0; k0 < K; k0 += 32) {
    // --- stage A: 128x32 fp32 -> bf16, coalesced 8 lanes/row ---
#pragma unroll
    for (int q = 0; q < 4; q++) {
      int row = q*32 + sr;
      int grow = bm + row;
      int kk = k0 + skq;
      float4 f4 = (kk < K1) ? *(const float4*)(A1 + (size_t)grow*K1 + kk)
                            : *(const float4*)(A2 + (size_t)grow*K2 + (kk - K1));
      ushort4 u;
      u.x = f2b(f4.x); u.y = f2b(f4.y); u.z = f2b(f4.z); u.w = f2b(f4.w);
      *(ushort4*)((char*)AsB + swz(row, skq)) = u;
    }
    // --- stage B: Bs[n][k] from Wt[n][k] (already bf16) ---
    {
      const unsigned short* s = Wt + (size_t)(bn + bn_)*K + k0 + bkh;
#pragma unroll
      for (int q = 0; q < 4; q++) {
        ushort4 u = *(const ushort4*)(s + q*4);
        *(ushort4*)((char*)BsB + swz(bn_, bkh + q*4)) = u;
      }
    }
    __syncthreads();
    const int fr = lane & 15, fk = (lane >> 4) * 8;
    bf16x8 af[4], bf[4];
#pragma unroll
    for (int i = 0; i < 4; i++)
      af[i] = *(bf16x8*)((char*)AsB + swz(wr + i*16 + fr, fk));
#pragma unroll
    for (int j = 0; j < 4; j++)
      bf[j] = *(bf16x8*)((char*)BsB + swz(wc + j*16 + fr, fk));
#pragma unroll
    for (int i = 0; i < 4; i++)
#pragma unroll
      for (int j = 0; j < 4; j++)
        acc[i][j] = __builtin_amdgcn_mfma_f32_16x16x32_bf16(af[i], bf[j], acc[i][j], 0, 0, 0);
    __syncthreads();
  }

  const float rscale = 1.f/sqrtf((float)K);
  float a2 = 0.f, inv1a2 = 1.f;
  if (FLAGS & F_RESID) { float al = alphap[0]; a2 = al*al; inv1a2 = 1.f/(1.f+a2); }
#pragma unroll
  for (int i = 0; i < 4; i++) {
#pragma unroll
    for (int r = 0; r < 4; r++) {
      int row = bm + wr + i*16 + ((lane >> 4) << 2) + r;
      float ev = (FLAGS & F_ENV) ? env[row] : 1.f;
#pragma unroll
      for (int j = 0; j < 4; j++) {
        int col = bn + wc + j*16 + (lane & 15);
        float v = acc[i][j][r]*rscale;
        if (FLAGS & F_SILU) v = v/(1.f+__expf(-v));
        if (FLAGS & F_ENV)  v *= ev;
        if (FLAGS & F_RESID) v = (Xres[(size_t)row*N+col] + a2*v)*inv1a2;
        Cout[(size_t)row*N+col] = v;
      }
    }
  }
}

// ---- weight convert + transpose: Wt[n][k] = bf16(W[k][n]), 9 weights fused ----
struct WDesc { const float* src; unsigned short* dst; int K; int lgN; };
struct WPack { WDesc d[9]; };
__global__ void wcvt_k(WPack p){
  WDesc d = p.d[blockIdx.y];
  int total = d.K << d.lgN;
  int gid = blockIdx.x*256 + threadIdx.x;
  if (gid >= total) return;
  int k = gid >> d.lgN, n = gid & ((1 << d.lgN) - 1);
  d.dst[(size_t)n*d.K + k] = f2b(d.src[gid]);
}

// Generic fp32 tiled GEMM (kept for small two-body layers).
template<int FLAGS>
__global__ __launch_bounds__(256) void gemm_k(
    const float* __restrict__ A1, const float* __restrict__ A2,
    int K1, int K, const float* __restrict__ W, int N,
    float* Cout,
    const float* __restrict__ env, const float* __restrict__ alphap,
    const float* Xres)
{
  __shared__ float As[16][68];
  __shared__ float Ws[16][68];
  const int tid = threadIdx.x;
  const int bm = blockIdx.x * 64;
  const int bn = blockIdx.y * 64;
  const int tx = tid & 15, ty = tid >> 4;
  const int K2 = K - K1;
  float acc[4][4] = {};
  for (int k0 = 0; k0 < K; k0 += 16) {
#pragma unroll
    for (int i = 0; i < 4; i++) {
      int idx = tid + i*256;
      int m = idx >> 4, kk = idx & 15;
      int k = k0 + kk;
      float v = 0.f;
      if (k < K) {
        int row = bm + m;
        v = (k < K1) ? A1[(size_t)row*K1 + k] : A2[(size_t)row*K2 + (k-K1)];
      }
      As[kk][m] = v;
    }
#pragma unroll
    for (int i = 0; i < 4; i++) {
      int idx = tid + i*256;
      int n = idx & 63, kk = idx >> 6;
      int k = k0 + kk, col = bn + n;
      Ws[kk][n] = (k < K && col < N) ? W[(size_t)k*N + col] : 0.f;
    }
    __syncthreads();
#pragma unroll
    for (int kk = 0; kk < 16; kk++) {
      float a[4], b[4];
#pragma unroll
      for (int i=0;i<4;i++) a[i] = As[kk][ty*4+i];
#pragma unroll
      for (int j=0;j<4;j++) b[j] = Ws[kk][tx*4+j];
#pragma unroll
      for (int i=0;i<4;i++)
#pragma unroll
        for (int j=0;j<4;j++)
          acc[i][j] += a[i]*b[j];
    }
    __syncthreads();
  }
  const float rscale = 1.f/sqrtf((float)K);
  float a2 = 0.f, inv1a2 = 1.f;
  if (FLAGS & F_RESID) { float al = alphap[0]; a2 = al*al; inv1a2 = 1.f/(1.f+a2); }
#pragma unroll
  for (int i=0;i<4;i++) {
    int row = bm + ty*4 + i;
    float ev = (FLAGS & F_ENV) ? env[row] : 1.f;
#pragma unroll
    for (int j=0;j<4;j++) {
      int col = bn + tx*4 + j;
      if (col >= N) continue;
      float v = acc[i][j]*rscale;
      if (FLAGS & F_SILU) v = v/(1.f+__expf(-v));
      if (FLAGS & F_ENV)  v *= ev;
      if (FLAGS & F_RESID) v = (Xres[(size_t)row*N+col] + a2*v)*inv1a2;
      Cout[(size_t)row*N+col] = v;
    }
  }
}

// dense to 16 outputs, K=256 fixed, scale 1/16, no activation
__global__ __launch_bounds__(256) void dense16_k(const float* __restrict__ A,
    const float* __restrict__ W, float* __restrict__ C)
{
  __shared__ float As[16*256];
  const int r0 = blockIdx.x << 4;
  const int tid = threadIdx.x;
  for (int i = tid; i < 16*256; i += 256)
    As[i] = A[((size_t)r0<<8) + i];
  __syncthreads();
  const int r = tid >> 4, n = tid & 15;
  float acc = 0.f;
#pragma unroll 8
  for (int k = 0; k < 256; k++)
    acc += As[(r<<8)+k] * W[(k<<4)+n];
  C[((size_t)(r0+r)<<4)+n] = acc * 0.0625f;
}

__global__ void edge_init_k(const float* __restrict__ vectors, const int* __restrict__ senders,
    const int* __restrict__ receivers, const int* __restrict__ species,
    const float* __restrict__ emb, float* __restrict__ envb, float* __restrict__ Yb,
    float* __restrict__ x72)
{
  const int e = blockIdx.x*256 + threadIdx.x;
  float vx = vectors[e*3+0], vy = vectors[e*3+1], vz = vectors[e*3+2];
  float d = sqrtf(vx*vx+vy*vy+vz*vz);
  float dd = (d==0.f) ? 1.f : d;
  float invd = 1.f/dd;
  float x = vx*invd, y = vy*invd, z = vz*invd;
  float d2=d*d, d3=d2*d, d6=d3*d3, d7=d6*d, d8=d7*d;
  float envv = (d<1.f) ? (1.f - 28.f*d6 + 48.f*d7 - 21.f*d8) : 0.f;
  envb[e] = envv;
  float mask = (d==0.f)?0.f:1.f;
  const float SQ2 = 1.41421356237309515f;
  const float PIf = 3.14159265358979323846f;
  float* xr = x72 + (size_t)e*72;
#pragma unroll
  for (int n=1;n<=8;n++)
    xr[n-1] = SQ2 * sinf((float)n*PIf*dd)*invd*envv*mask;
  int sp_s = species[senders[e]], sp_r = species[receivers[e]];
  const float* es_ = emb + (size_t)sp_s*32;
  const float* er_ = emb + (size_t)sp_r*32;
#pragma unroll 8
  for (int k=0;k<32;k++){ xr[8+k] = es_[k]*mask; xr[40+k] = er_[k]*mask; }
  // real spherical harmonics up to l=3
  float x2=x*x, y2=y*y, z2=z*z;
  const float s3=1.7320508075688772f, s15=3.872983346207417f, s5=2.23606797749979f;
  const float s358=2.0916500663351889f, s105=10.246950765959598f;
  const float s218=1.6201851746019651f, s7=2.6457513110645907f;
  float* Yr = Yb + ((size_t)e<<4);
  Yr[0]=1.f;           Yr[1]=s3*y;          Yr[2]=s3*z;           Yr[3]=s3*x;
  Yr[4]=s15*x*y;       Yr[5]=s15*y*z;       Yr[6]=0.5f*s5*(3.f*z2-1.f);
  Yr[7]=s15*x*z;       Yr[8]=0.5f*s15*(x2-y2);
  Yr[9]=s358*y*(3.f*x2-y2);  Yr[10]=s105*x*y*z;  Yr[11]=s218*y*(5.f*z2-1.f);
  Yr[12]=0.5f*s7*(5.f*z2-3.f)*z;  Yr[13]=s218*x*(5.f*z2-1.f);
  Yr[14]=0.5f*s105*(x2-y2)*z;     Yr[15]=s358*x*(x2-y2);
}

// V[e,m,k] = w0[e,m]*Y[e,k]
__global__ void vinit_k(const float* __restrict__ w0, const float* __restrict__ Y,
                        float* __restrict__ V)
{
  const int gid = blockIdx.x*256 + threadIdx.x;
  const int e = gid >> 8, idx = gid & 255;
  V[gid] = w0[(e<<4)+(idx>>4)] * Y[(e<<4)+(idx&15)];
}

// node[senders[e], m, k] += w[e,m]*Y[e,k]
__global__ void scatter_k(const float* __restrict__ w, const float* __restrict__ Y,
                          const int* __restrict__ senders, float* node)
{
  const int gid = blockIdx.x*256 + threadIdx.x;
  const int e = gid >> 8, idx = gid & 255;
  float v = w[(e<<4) + (idx>>4)] * Y[(e<<4) + (idx&15)];
  atomicAdd(&node[((size_t)senders[e]<<8) + idx], v);
}

// layer-1 TP: full tensor product into LDS, then dense_axis -> Vn, plus tp0 out.
__global__ __launch_bounds__(256) void tp1_k(
    const float* __restrict__ node, const float* V,
    const int* __restrict__ senders, const float* __restrict__ varepsp,
    const int* __restrict__ pmeta, const int* __restrict__ ccnt,
    const int* __restrict__ entIJ, const float* __restrict__ entVal,
    const float* __restrict__ Wv1, const float* __restrict__ Wv2,
    const float* __restrict__ Wv3,
    float* Vn, float* __restrict__ tp0,
    int ntask, int base1, int C1, int base2, int C2, int base3, int C3)
{
  __shared__ float As[16*17], Bs[16*17];
  __shared__ float tp[2496];
  const int e = blockIdx.x;
  const int tid = threadIdx.x;
  float ve = varepsp[0];
  float eps = rsqrtf(1.f + ve*ve);
  int s = senders[e];
  {
    float av = node[((size_t)s<<8) + tid] * eps;
    float bv = V[((size_t)e<<8) + tid];
    int m = tid >> 4, a = tid & 15;
    As[a*17+m] = av;
    Bs[a*17+m] = bv;
  }
  __syncthreads();
  for (int task = tid; task < ntask; task += 256) {
    int p = task >> 4, m = task & 15;
    int kd    = pmeta[p*4+3];
    int tpOff = pmeta[p*4+0] + m*kd;
    int t     = pmeta[p*4+1];
    for (int c = 0; c < kd; c++) {
      int cnt = ccnt[p*8+c];
      float acc = 0.f;
      for (int i = 0; i < cnt; i++, t++) {
        int ij = entIJ[t];
        acc += entVal[t] * As[(ij&255)*17+m] * Bs[((ij>>8)&255)*17+m];
      }
      tp[tpOff + c] = acc;
    }
  }
  __syncthreads();
  if (tid < 64) tp0[((size_t)e<<6) + tid] = tp[tid];
  const int d = tid & 15, kabs = tid >> 4;
  float outv = 0.f;
  if (kabs >= 1) {
    int base, C, kd, kloc; const float* Wv;
    if (kabs < 4)      { base=base1; C=C1; kd=3; kloc=kabs-1; Wv=Wv1; }
    else if (kabs < 9) { base=base2; C=C2; kd=5; kloc=kabs-4; Wv=Wv2; }
    else               { base=base3; C=C3; kd=7; kloc=kabs-9; Wv=Wv3; }
    float acc = 0.f;
    for (int c = 0; c < C; c++)
      acc += tp[base + c*kd + kloc] * Wv[(c<<4) + d];
    outv = acc * rsqrtf((float)C);
  }
  Vn[((size_t)e<<8) + (d<<4) + kabs] = outv;
}

// layer-2 TP: l3=0 only (slots 0..3), one thread per (e, p*16+m).
__global__ void tp2_k(const float* __restrict__ node, const float* __restrict__ Vn,
    const int* __restrict__ senders, const float* __restrict__ varepsp,
    const int* __restrict__ pmeta, const int* __restrict__ entIJ,
    const float* __restrict__ entVal, float* __restrict__ tp0)
{
  const int gid = blockIdx.x*256 + threadIdx.x;
  const int e = gid >> 6, c = gid & 63;
  const int p = c >> 4, m = c & 15;
  float ve = varepsp[0];
  float eps = rsqrtf(1.f + ve*ve);
  int s = senders[e];
  const float* Am = &node[((size_t)s<<8) + (m<<4)];
  const float* Bm = &Vn[((size_t)e<<8) + (m<<4)];
  int es = pmeta[p*4+1], ec = pmeta[p*4+2];
  float acc = 0.f;
  for (int t=0;t<ec;t++){
    int ij = entIJ[es+t];
    acc += entVal[es+t] * Am[ij&255] * Bm[(ij>>8)&255];
  }
  tp0[((size_t)e<<6) + pmeta[p*4+0] + m] = acc * eps;
}

// out[e] = env[e] * dot(X[e,:128], Wout) / sqrt(128)
__global__ void final_k(const float* __restrict__ X, const float* __restrict__ Wout,
                        const float* __restrict__ env, float* __restrict__ out)
{
  const int e = blockIdx.x*256 + threadIdx.x;
  float acc = 0.f;
#pragma unroll 16
  for (int k=0;k<128;k++) acc += X[((size_t)e<<7)+k]*Wout[k];
  out[e] = env[e]*acc*0.088388347648318447f;
}

// ============================ host launcher ============================

static void launch_gemm(int flags, const float* A1, const float* A2, int K1, int K,
    const float* W, int N, float* C, const float* env, const float* alphap,
    const float* Xres, hipStream_t stream)
{
  dim3 grid(E_EDGES/64, (N+63)/64);
  switch(flags){
    case F_NONE:        gemm_k<F_NONE>       <<<grid,256,0,stream>>>(A1,A2,K1,K,W,N,C,env,alphap,Xres); break;
    case F_SILU:        gemm_k<F_SILU>       <<<grid,256,0,stream>>>(A1,A2,K1,K,W,N,C,env,alphap,Xres); break;
    case F_ENV:         gemm_k<F_ENV>        <<<grid,256,0,stream>>>(A1,A2,K1,K,W,N,C,env,alphap,Xres); break;
    case F_ENV|F_RESID: gemm_k<F_ENV|F_RESID><<<grid,256,0,stream>>>(A1,A2,K1,K,W,N,C,env,alphap,Xres); break;
  }
}

static void launch_mgemm(int flags, const float* A1, const float* A2, int K1, int K,
    const unsigned short* Wt, int N, float* C, const float* env, const float* alphap,
    const float* Xres, hipStream_t stream)
{
  dim3 grid(E_EDGES/128, N/128);
  switch(flags){
    case F_NONE:        mgemm_k<F_NONE>       <<<grid,256,0,stream>>>(A1,A2,K1,K,Wt,N,C,env,alphap,Xres); break;
    case F_SILU:        mgemm_k<F_SILU>       <<<grid,256,0,stream>>>(A1,A2,K1,K,Wt,N,C,env,alphap,Xres); break;
    case F_ENV:         mgemm_k<F_ENV>        <<<grid,256,0,stream>>>(A1,A2,K1,K,Wt,N,C,env,alphap,Xres); break;
    case F_ENV|F_RESID: mgemm_k<F_ENV|F_RESID><<<grid,256,0,stream>>>(A1,A2,K1,K,Wt,N,C,env,alphap,Xres); break;
  }
}

extern "C" void kernel_launch(void* const* d_in, const int* in_sizes, int n_in,
                              void* d_out, int out_size, void* d_ws, size_t ws_size,
                              hipStream_t stream)
{
  const float* vectors = (const float*)d_in[0];
  const float* vareps  = (const float*)d_in[1];
  const float* alpha   = (const float*)d_in[2];
  const float* emb     = (const float*)d_in[3];
  const float* W_tb1   = (const float*)d_in[4];
  const float* W_tb2   = (const float*)d_in[5];
  const float* W_tb3   = (const float*)d_in[6];
  const float* W_tb4   = (const float*)d_in[7];
  const float* W_w0    = (const float*)d_in[8];
  const float* W_w1    = (const float*)d_in[9];
  const float* W_l11   = (const float*)d_in[10];
  const float* W_l12   = (const float*)d_in[11];
  const float* W_l13   = (const float*)d_in[12];
  const float* W_v1    = (const float*)d_in[13];
  const float* W_v2    = (const float*)d_in[14];
  const float* W_v3    = (const float*)d_in[15];
  const float* W_w2    = (const float*)d_in[16];
  const float* W_l21   = (const float*)d_in[17];
  const float* W_l22   = (const float*)d_in[18];
  const float* W_l23   = (const float*)d_in[19];
  const float* W_h     = (const float*)d_in[20];
  const float* W_out   = (const float*)d_in[21];
  const int* senders   = (const int*)d_in[22];
  const int* receivers = (const int*)d_in[23];
  const int* species   = (const int*)d_in[24];

  static cgt::Tables tb;
  cgt::build(tb);

  char* ws = (char*)d_ws;
  size_t off = 0;
  auto alloc = [&](size_t bytes)->void*{
    void* p = ws + off; off += (bytes + 255) & ~(size_t)255; return p;
  };
  float* t_val = (float*)alloc(sizeof(tb.val));
  int*   t_ij  = (int*)  alloc(sizeof(tb.ij));
  int*   t_pm  = (int*)  alloc(sizeof(tb.pmeta));
  int*   t_cc  = (int*)  alloc(sizeof(tb.ccnt));
  float* envb  = (float*)alloc((size_t)E_EDGES*4);
  float* Yb    = (float*)alloc((size_t)E_EDGES*16*4);
  float* xb    = (float*)alloc((size_t)E_EDGES*256*4);
  float* Vb    = (float*)alloc((size_t)E_EDGES*256*4);
  float* bufA  = (float*)alloc((size_t)E_EDGES*256*4);
  float* bufB  = (float*)alloc((size_t)E_EDGES*256*4);
  float* tp0b  = (float*)alloc((size_t)E_EDGES*64*4);
  float* wb    = (float*)alloc((size_t)E_EDGES*16*4);
  float* nodeb = (float*)alloc((size_t)NNODES*256*4);
  // bf16 transposed weights
  unsigned short* Wt_tb3 = (unsigned short*)alloc(64*128*2);
  unsigned short* Wt_tb4 = (unsigned short*)alloc(128*256*2);
  unsigned short* Wt_l11 = (unsigned short*)alloc(320*256*2);
  unsigned short* Wt_l12 = (unsigned short*)alloc(256*256*2);
  unsigned short* Wt_l13 = (unsigned short*)alloc(256*256*2);
  unsigned short* Wt_l21 = (unsigned short*)alloc(320*256*2);
  unsigned short* Wt_l22 = (unsigned short*)alloc(256*256*2);
  unsigned short* Wt_l23 = (unsigned short*)alloc(256*256*2);
  unsigned short* Wt_h   = (unsigned short*)alloc(256*128*2);
  if (off > ws_size) {
    fprintf(stderr, "[allegro] workspace too small: need %zu, have %zu\n", off, ws_size);
    return;
  }

  hipMemcpyAsync(t_val, tb.val,   sizeof(tb.val),   hipMemcpyHostToDevice, stream);
  hipMemcpyAsync(t_ij,  tb.ij,    sizeof(tb.ij),    hipMemcpyHostToDevice, stream);
  hipMemcpyAsync(t_pm,  tb.pmeta, sizeof(tb.pmeta), hipMemcpyHostToDevice, stream);
  hipMemcpyAsync(t_cc,  tb.ccnt,  sizeof(tb.ccnt),  hipMemcpyHostToDevice, stream);

  // weight convert+transpose (bf16), one fused launch
  {
    WPack p;
    p.d[0] = { W_tb3, Wt_tb3,  64, 7 };
    p.d[1] = { W_tb4, Wt_tb4, 128, 8 };
    p.d[2] = { W_l11, Wt_l11, 320, 8 };
    p.d[3] = { W_l12, Wt_l12, 256, 8 };
    p.d[4] = { W_l13, Wt_l13, 256, 8 };
    p.d[5] = { W_l21, Wt_l21, 320, 8 };
    p.d[6] = { W_l22, Wt_l22, 256, 8 };
    p.d[7] = { W_l23, Wt_l23, 256, 8 };
    p.d[8] = { W_h,   Wt_h,   256, 7 };
    dim3 g(320, 9);
    wcvt_k<<<g, 256, 0, stream>>>(p);
  }

  const int ntask = tb.npaths * 16;
  const int b1 = tb.l3base[1], b2 = tb.l3base[2], b3 = tb.l3base[3];
  const int C1 = tb.l3np[1]*16, C2 = tb.l3np[2]*16, C3 = tb.l3np[3]*16;

  // 1. edge features + Y + env
  edge_init_k<<<E_EDGES/256, 256, 0, stream>>>(vectors, senders, receivers, species,
                                               emb, envb, Yb, bufA);
  // 2. two-body MLP: 72 -> 32 -> 64 (fp32) -> 128 -> 256 (bf16 MFMA)
  launch_gemm (F_SILU, bufA, nullptr, 72, 72,  W_tb1, 32,   bufB, envb, alpha, nullptr, stream);
  launch_gemm (F_SILU, bufB, nullptr, 32, 32,  W_tb2, 64,   bufA, envb, alpha, nullptr, stream);
  launch_mgemm(F_SILU, bufA, nullptr, 64, 64,  Wt_tb3, 128, bufB, envb, alpha, nullptr, stream);
  launch_mgemm(F_ENV,  bufB, nullptr, 128,128, Wt_tb4, 256, xb,   envb, alpha, nullptr, stream);
  // 3. V = dense(x,W_w0) outer Y
  dense16_k<<<E_EDGES/16, 256, 0, stream>>>(xb, W_w0, wb);
  vinit_k<<<E_EDGES, 256, 0, stream>>>(wb, Yb, Vb);

  // ---- layer 1 ----
  dense16_k<<<E_EDGES/16, 256, 0, stream>>>(xb, W_w1, wb);
  hipMemsetAsync(nodeb, 0, (size_t)NNODES*256*4, stream);
  scatter_k<<<E_EDGES, 256, 0, stream>>>(wb, Yb, senders, nodeb);
  tp1_k<<<E_EDGES, 256, 0, stream>>>(nodeb, Vb, senders, vareps, t_pm, t_cc, t_ij, t_val,
                                     W_v1, W_v2, W_v3, Vb, tp0b,
                                     ntask, b1, C1, b2, C2, b3, C3);
  launch_mgemm(F_SILU,        xb,   tp0b,   256, 320, Wt_l11, 256, bufB, envb, alpha, nullptr, stream);
  launch_mgemm(F_SILU,        bufB, nullptr,256, 256, Wt_l12, 256, bufA, envb, alpha, nullptr, stream);
  launch_mgemm(F_ENV|F_RESID, bufA, nullptr,256, 256, Wt_l13, 256, xb,   envb, alpha, xb,      stream);

  // ---- layer 2 (lmax_out = 0) ----
  dense16_k<<<E_EDGES/16, 256, 0, stream>>>(xb, W_w2, wb);
  hipMemsetAsync(nodeb, 0, (size_t)NNODES*256*4, stream);
  scatter_k<<<E_EDGES, 256, 0, stream>>>(wb, Yb, senders, nodeb);
  tp2_k<<<E_EDGES*64/256, 256, 0, stream>>>(nodeb, Vb, senders, vareps, t_pm, t_ij,
                                            t_val, tp0b);
  launch_mgemm(F_SILU,        xb,   tp0b,   256, 320, Wt_l21, 256, bufB, envb, alpha, nullptr, stream);
  launch_mgemm(F_SILU,        bufB, nullptr,256, 256, Wt_l22, 256, bufA, envb, alpha, nullptr, stream);
  launch_mgemm(F_ENV|F_RESID, bufA, nullptr,256, 256, Wt_l23, 256, xb,   envb, alpha, xb,      stream);

  // ---- head ----
  launch_mgemm(F_NONE, xb, nullptr, 256, 256, Wt_h, 128, bufB, envb, alpha, nullptr, stream);
  final_k<<<E_EDGES/256, 256, 0, stream>>>(bufB, W_out, envb, (float*)d_out);
}